// Round 2
// baseline (62.604 us; speedup 1.0000x reference)
//
#include <hip/hip_runtime.h>
#include <cstdint>
#include <cstddef>

// Problem constants
#define B_ 256
#define D_ 512
#define P_ 128
#define E_ 128

typedef unsigned short u16;
typedef unsigned int   u32;
typedef __bf16  bf16x8_t __attribute__((ext_vector_type(8)));
typedef float   f32x4_t  __attribute__((ext_vector_type(4)));
typedef u16     u16x8_t  __attribute__((ext_vector_type(8)));

__device__ __forceinline__ u16 f2bf(float f) {
  // round-to-nearest-even f32 -> bf16 (finite inputs)
  union { float f; unsigned int u; } c; c.f = f;
  unsigned int u = c.u;
  unsigned int r = (u + 0x7FFFu + ((u >> 16) & 1u)) >> 16;
  return (u16)r;
}
__device__ __forceinline__ u32 pk2bf(float a, float b) {
  return (u32)f2bf(a) | ((u32)f2bf(b) << 16);
}

// ---------------------------------------------------------------------------
// Pass 1: transpose + convert x f32 -> bf16.
// src viewed as [outer=b][R=512 d][C=128 p] f32; dst xT[p][b][d] bf16.
// ---------------------------------------------------------------------------
__global__ __launch_bounds__(256) void transpose_cvt_kernel(
    const float* __restrict__ src, u16* __restrict__ dst) {
  __shared__ float tile[64][65];  // +1 pad: conflict-free column reads

  const int o  = blockIdx.x;          // b
  const int r0 = blockIdx.y * 64;     // d block
  const int c0 = blockIdx.z * 64;     // p block
  const int t  = threadIdx.x;

  const float* s = src + (size_t)o * D_ * 128 + (size_t)r0 * 128 + c0;

  {
    const int lr = t >> 4;          // 0..15
    const int lc = (t & 15) * 4;    // 0..60
    #pragma unroll
    for (int it = 0; it < 4; ++it) {
      const int r = lr + it * 16;
      const float4 v = *reinterpret_cast<const float4*>(s + (size_t)r * 128 + lc);
      tile[r][lc + 0] = v.x; tile[r][lc + 1] = v.y;
      tile[r][lc + 2] = v.z; tile[r][lc + 3] = v.w;
    }
  }
  __syncthreads();

  {
    const int wc = t >> 3;          // 0..31 (col within tile = p)
    const int wd = (t & 7) * 8;     // 0..56 (row chunk base = d)
    #pragma unroll
    for (int it = 0; it < 2; ++it) {
      const int c = wc + it * 32;
      u16x8_t pkv;
      #pragma unroll
      for (int j = 0; j < 8; ++j) pkv[j] = f2bf(tile[wd + j][c]);
      *reinterpret_cast<u16x8_t*>(dst + (size_t)(c0 + c) * (B_ * D_) +
                                  (size_t)o * D_ + r0 + wd) = pkv;
    }
  }
}

// ---------------------------------------------------------------------------
// Pass 2: per-p bf16 TN GEMM, 128x128 tile, BK=32, 4 waves, double-buffered
// 2-phase pipeline (stage k+1 before compute k).
//   A = xT[p][b][d] bf16 (K-contiguous) -> global_load_lds width 16
//   B = W[p][d][e]  f32  -> reg-load float4, cvt bf16, ds_write transposed
//   out[b][e][p] = acc + bias[p][e]
// Grid 256 WGs, XCD-swizzled: xcd = wg&7 owns p in [16*xcd, 16*xcd+16).
// ---------------------------------------------------------------------------
__global__ __launch_bounds__(256) void gemm_kernel(
    const u16* __restrict__ xT, const float* __restrict__ W,
    const float* __restrict__ bias, float* __restrict__ out) {
  __shared__ __attribute__((aligned(16))) u16 As[2][128 * 32];
  __shared__ __attribute__((aligned(16))) u16 Bs[2][128 * 32];

  const int wg  = blockIdx.x;
  const int xcd = wg & 7;
  const int i   = wg >> 3;            // 0..31
  const int p   = xcd * 16 + (i & 15);
  const int b0  = (i >> 4) * 128;     // 0 or 128

  const int t    = threadIdx.x;
  const int lane = t & 63;
  const int wv   = t >> 6;            // wave 0..3
  const int wr   = wv >> 1;           // wave row (2x2 wave grid)
  const int wc   = wv & 1;            // wave col

  const u16*   Ag = xT + (size_t)p * (B_ * D_) + (size_t)b0 * D_;
  const float* Wg = W + (size_t)p * (D_ * E_);

  // A staging: 16B chunk per thread x2; wave-uniform LDS base + lane*16
  const int r1 = t >> 2;              // row 0..63
  const int h1 = (t & 3) * 8;         // elem offset within row
  // B staging: thread -> (k-pair, e-quad)
  const int k2 = t & 15;              // d-pair: d = 2*k2, 2*k2+1
  const int eq = t >> 4;              // e = 4*eq (and +64 second half)

  const int fr = lane & 15;
  const int fk = (lane >> 4) * 8;

  f32x4_t acc[4][4] = {};
  float4 wa0, wa1, wb0, wb1;

#define STAGE_A(buf, d0) do { \
    __builtin_amdgcn_global_load_lds( \
        (const __attribute__((address_space(1))) void*)(Ag + (size_t)r1 * D_ + (d0) + h1), \
        (__attribute__((address_space(3))) void*)&As[buf][wv * 512], 16, 0, 0); \
    __builtin_amdgcn_global_load_lds( \
        (const __attribute__((address_space(1))) void*)(Ag + (size_t)(r1 + 64) * D_ + (d0) + h1), \
        (__attribute__((address_space(3))) void*)&As[buf][2048 + wv * 512], 16, 0, 0); \
  } while (0)

#define LOAD_B(d0) do { \
    const float* wp = Wg + (size_t)((d0) + 2 * k2) * E_ + 4 * eq; \
    wa0 = *reinterpret_cast<const float4*>(wp); \
    wa1 = *reinterpret_cast<const float4*>(wp + E_); \
    wb0 = *reinterpret_cast<const float4*>(wp + 64); \
    wb1 = *reinterpret_cast<const float4*>(wp + E_ + 64); \
  } while (0)

  // Bs element (e, k) at index e*32 + k; rows advance by 16 u32.
#define WRITE_B(buf) do { \
    u32* q0 = reinterpret_cast<u32*>(&Bs[buf][(4 * eq) * 32 + 2 * k2]); \
    q0[0]  = pk2bf(wa0.x, wa1.x); \
    q0[16] = pk2bf(wa0.y, wa1.y); \
    q0[32] = pk2bf(wa0.z, wa1.z); \
    q0[48] = pk2bf(wa0.w, wa1.w); \
    u32* q1 = reinterpret_cast<u32*>(&Bs[buf][(4 * eq + 64) * 32 + 2 * k2]); \
    q1[0]  = pk2bf(wb0.x, wb1.x); \
    q1[16] = pk2bf(wb0.y, wb1.y); \
    q1[32] = pk2bf(wb0.z, wb1.z); \
    q1[48] = pk2bf(wb0.w, wb1.w); \
  } while (0)

  // prologue: stage K-tile 0 into buffer 0
  STAGE_A(0, 0);
  LOAD_B(0);
  WRITE_B(0);
  __syncthreads();

  for (int kt = 0; kt < 16; ++kt) {
    const int cur = kt & 1;
    const int nxt = cur ^ 1;
    if (kt < 15) {
      STAGE_A(nxt, (kt + 1) * 32);   // async global->LDS, in flight over MFMA
      LOAD_B((kt + 1) * 32);         // global->reg, in flight over MFMA
    }

    bf16x8_t af[4], bfr[4];
    #pragma unroll
    for (int ii = 0; ii < 4; ++ii)
      af[ii] = *reinterpret_cast<const bf16x8_t*>(&As[cur][(wr * 64 + ii * 16 + fr) * 32 + fk]);
    #pragma unroll
    for (int jj = 0; jj < 4; ++jj)
      bfr[jj] = *reinterpret_cast<const bf16x8_t*>(&Bs[cur][(wc * 64 + jj * 16 + fr) * 32 + fk]);
    #pragma unroll
    for (int ii = 0; ii < 4; ++ii)
      #pragma unroll
      for (int jj = 0; jj < 4; ++jj)
        acc[ii][jj] = __builtin_amdgcn_mfma_f32_16x16x32_bf16(af[ii], bfr[jj], acc[ii][jj], 0, 0, 0);

    if (kt < 15) WRITE_B(nxt);       // cvt + LDS write after MFMA issue
    __syncthreads();
  }
#undef STAGE_A
#undef LOAD_B
#undef WRITE_B

  // epilogue: C/D layout col=lane&15, row=(lane>>4)*4+reg
  const int q4 = (lane >> 4) * 4;
  #pragma unroll
  for (int jj = 0; jj < 4; ++jj) {
    const int e  = wc * 64 + jj * 16 + fr;
    const float bv = bias[p * E_ + e];
    #pragma unroll
    for (int ii = 0; ii < 4; ++ii) {
      const int r0 = b0 + wr * 64 + ii * 16 + q4;
      #pragma unroll
      for (int rg = 0; rg < 4; ++rg) {
        out[((size_t)(r0 + rg) * E_ + e) * P_ + p] = acc[ii][jj][rg] + bv;
      }
    }
  }
}

// ---------------------------------------------------------------------------
// Fallback (only if workspace is too small): naive but correct.
// ---------------------------------------------------------------------------
__global__ __launch_bounds__(256) void naive_kernel(
    const float* __restrict__ x, const float* __restrict__ W,
    const float* __restrict__ bias, float* __restrict__ out) {
  const size_t idx = (size_t)blockIdx.x * 256 + threadIdx.x;
  const int p = (int)(idx & 127);
  const int e = (int)((idx >> 7) & 127);
  const int b = (int)(idx >> 14);
  float acc = bias[p * E_ + e];
  const float* xp = x + (size_t)b * D_ * P_ + p;
  const float* wp = W + (size_t)p * D_ * E_ + e;
  for (int d = 0; d < D_; ++d) acc += xp[(size_t)d * P_] * wp[(size_t)d * E_];
  out[idx] = acc;
}

extern "C" void kernel_launch(void* const* d_in, const int* in_sizes, int n_in,
                              void* d_out, int out_size, void* d_ws, size_t ws_size,
                              hipStream_t stream) {
  (void)in_sizes; (void)n_in; (void)out_size;
  const float* x    = (const float*)d_in[0];   // [B,D,P] f32
  const float* W    = (const float*)d_in[1];   // [P,D,E] f32
  const float* bias = (const float*)d_in[2];   // [P,E]   f32
  float* out = (float*)d_out;                  // [B,E,P] f32

  const size_t xT_bytes = (size_t)P_ * B_ * D_ * 2;   // 32 MiB

  if (ws_size < xT_bytes) {
    naive_kernel<<<dim3((B_ * E_ * P_) / 256), dim3(256), 0, stream>>>(x, W, bias, out);
    return;
  }

  u16* xT = (u16*)d_ws;                                 // [P][B][D] bf16

  transpose_cvt_kernel<<<dim3(B_, 8, 2), 256, 0, stream>>>(x, xT);
  gemm_kernel<<<dim3(256), 256, 0, stream>>>(xT, W, bias, out);
}

// Round 3
// 57.769 us; speedup vs baseline: 1.0837x; 1.0837x over previous
//
#include <hip/hip_runtime.h>
#include <cstdint>
#include <cstddef>

// Problem constants
#define B_ 256
#define D_ 512
#define P_ 128
#define E_ 128

typedef unsigned short u16;
typedef unsigned int   u32;
typedef __bf16  bf16x8_t __attribute__((ext_vector_type(8)));
typedef float   f32x4_t  __attribute__((ext_vector_type(4)));
typedef u16     u16x8_t  __attribute__((ext_vector_type(8)));

__device__ __forceinline__ u16 f2bf(float f) {
  // round-to-nearest-even f32 -> bf16 (finite inputs)
  union { float f; unsigned int u; } c; c.f = f;
  unsigned int u = c.u;
  unsigned int r = (u + 0x7FFFu + ((u >> 16) & 1u)) >> 16;
  return (u16)r;
}
__device__ __forceinline__ u32 pk2bf(float a, float b) {
  return (u32)f2bf(a) | ((u32)f2bf(b) << 16);
}

// ---------------------------------------------------------------------------
// Pass 1: transpose + convert x f32 -> bf16.
// src viewed as [b][512 d][128 p] f32; dst xT[p][b][d] bf16.
// ---------------------------------------------------------------------------
__global__ __launch_bounds__(256) void transpose_cvt_kernel(
    const float* __restrict__ src, u16* __restrict__ dst) {
  __shared__ float tile[64][65];

  const int o  = blockIdx.x;          // b
  const int r0 = blockIdx.y * 64;     // d block
  const int c0 = blockIdx.z * 64;     // p block
  const int t  = threadIdx.x;

  const float* s = src + (size_t)o * D_ * 128 + (size_t)r0 * 128 + c0;

  {
    const int lr = t >> 4;
    const int lc = (t & 15) * 4;
    #pragma unroll
    for (int it = 0; it < 4; ++it) {
      const int r = lr + it * 16;
      const float4 v = *reinterpret_cast<const float4*>(s + (size_t)r * 128 + lc);
      tile[r][lc + 0] = v.x; tile[r][lc + 1] = v.y;
      tile[r][lc + 2] = v.z; tile[r][lc + 3] = v.w;
    }
  }
  __syncthreads();

  {
    const int wc = t >> 3;
    const int wd = (t & 7) * 8;
    #pragma unroll
    for (int it = 0; it < 2; ++it) {
      const int c = wc + it * 32;
      u16x8_t pkv;
      #pragma unroll
      for (int j = 0; j < 8; ++j) pkv[j] = f2bf(tile[wd + j][c]);
      *reinterpret_cast<u16x8_t*>(dst + (size_t)(c0 + c) * (B_ * D_) +
                                  (size_t)o * D_ + r0 + wd) = pkv;
    }
  }
}

// ---------------------------------------------------------------------------
// Pass 2: per-p bf16 TN GEMM. Tile 64(b) x 64(e) x BK=64, 4 waves (2x2 of
// 32x32), double-buffered LDS, 8 K-steps. Grid = 128p x 4bt x 2et = 1024 WGs
// = 4 WG/CU (latency hiding via co-resident WGs). XOR chunk-swizzle
// (chunk ^= row&7) on both A (pre-swizzled global source, linear LDS dest)
// and B (swizzled ds_write + swizzled read) -> conflict-free ds_read_b128.
// ---------------------------------------------------------------------------

// swizzled elem index of 16B chunk g (0..7) in row `row` of a [64]x[64]-u16 tile
#define SWZ_ELEM(row, g) (((row) << 6) + ((((g) ^ ((row) & 7))) << 3))
// swizzled u32 index for k-pair kk (0..31) in row er of the same tile
#define SWZ_BU32(er, kk) (((er) << 5) + ((((kk) >> 2) ^ ((er) & 7)) << 2) + ((kk) & 3))

__global__ __launch_bounds__(256, 4) void gemm_kernel(
    const u16* __restrict__ xT, const float* __restrict__ W,
    const float* __restrict__ bias, float* __restrict__ out) {
  __shared__ __attribute__((aligned(16))) u16 As[2][64 * 64];
  __shared__ __attribute__((aligned(16))) u16 Bs[2][64 * 64];

  const int wg   = blockIdx.x;
  const int xcd  = wg & 7;
  const int i    = wg >> 3;            // 0..127
  const int p    = xcd * 16 + (i & 15);
  const int tile = i >> 4;             // 0..7
  const int b0   = (tile & 3) * 64;
  const int e0t  = (tile >> 2) * 64;

  const int t    = threadIdx.x;
  const int lane = t & 63;
  const int wv   = t >> 6;
  const int wr   = wv >> 1;            // wave row (b half)
  const int wc   = wv & 1;             // wave col (e half)

  const u16*   Ag = xT + (size_t)p * (B_ * D_) + (size_t)b0 * D_;
  const float* Wg = W + (size_t)p * (D_ * E_) + e0t;

  // A staging: chunks c = t and t+256 of the 64x64 bf16 tile (8 chunks/row).
  // LDS dest linear (chunk c -> byte 16*c); global source chunk pre-swizzled.
  const int r1 = t >> 3;                          // row of chunk t (row of t+256 = r1+32)
  const int sw = (((t & 7) ^ (r1 & 7)) << 3);     // elem offset of swizzled source chunk
  // B staging: k-pair k2, e-quad eq
  const int k2 = t & 31;
  const int eq = t >> 5;               // 0..7 -> e = 4*eq (+32 for second half)

  const int fr = lane & 15;
  const int fq = lane >> 4;            // 0..3

  f32x4_t acc[2][2] = {};
  float4 wa0, wa1, wb0, wb1;

#define STAGE_A(buf, d0) do { \
    __builtin_amdgcn_global_load_lds( \
        (const __attribute__((address_space(1))) void*)(Ag + (size_t)r1 * D_ + (d0) + sw), \
        (__attribute__((address_space(3))) void*)&As[buf][wv * 512], 16, 0, 0); \
    __builtin_amdgcn_global_load_lds( \
        (const __attribute__((address_space(1))) void*)(Ag + (size_t)(r1 + 32) * D_ + (d0) + sw), \
        (__attribute__((address_space(3))) void*)&As[buf][2048 + wv * 512], 16, 0, 0); \
  } while (0)

#define LOAD_B(d0) do { \
    const float* wp = Wg + (size_t)((d0) + 2 * k2) * E_ + 4 * eq; \
    wa0 = *reinterpret_cast<const float4*>(wp); \
    wa1 = *reinterpret_cast<const float4*>(wp + E_); \
    wb0 = *reinterpret_cast<const float4*>(wp + 32); \
    wb1 = *reinterpret_cast<const float4*>(wp + E_ + 32); \
  } while (0)

#define WRITE_B(buf) do { \
    u32* bs = reinterpret_cast<u32*>(&Bs[buf][0]); \
    const int e = 4 * eq; \
    bs[SWZ_BU32(e + 0, k2)] = pk2bf(wa0.x, wa1.x); \
    bs[SWZ_BU32(e + 1, k2)] = pk2bf(wa0.y, wa1.y); \
    bs[SWZ_BU32(e + 2, k2)] = pk2bf(wa0.z, wa1.z); \
    bs[SWZ_BU32(e + 3, k2)] = pk2bf(wa0.w, wa1.w); \
    bs[SWZ_BU32(e + 32, k2)] = pk2bf(wb0.x, wb1.x); \
    bs[SWZ_BU32(e + 33, k2)] = pk2bf(wb0.y, wb1.y); \
    bs[SWZ_BU32(e + 34, k2)] = pk2bf(wb0.z, wb1.z); \
    bs[SWZ_BU32(e + 35, k2)] = pk2bf(wb0.w, wb1.w); \
  } while (0)

  // prologue: K-tile 0 into buffer 0
  STAGE_A(0, 0);
  LOAD_B(0);
  WRITE_B(0);
  __syncthreads();

  for (int kt = 0; kt < 8; ++kt) {
    const int cur = kt & 1;
    const int nxt = cur ^ 1;
    if (kt < 7) {
      STAGE_A(nxt, (kt + 1) * 64);   // async global->LDS, in flight over MFMA
      LOAD_B((kt + 1) * 64);         // global->reg, in flight over MFMA
    }

    bf16x8_t af[2][2], bfr[2][2];
    #pragma unroll
    for (int ii = 0; ii < 2; ++ii) {
      const int row = wr * 32 + ii * 16 + fr;
      #pragma unroll
      for (int kh = 0; kh < 2; ++kh)
        af[ii][kh] = *reinterpret_cast<const bf16x8_t*>(&As[cur][SWZ_ELEM(row, kh * 4 + fq)]);
    }
    #pragma unroll
    for (int jj = 0; jj < 2; ++jj) {
      const int row = wc * 32 + jj * 16 + fr;
      #pragma unroll
      for (int kh = 0; kh < 2; ++kh)
        bfr[jj][kh] = *reinterpret_cast<const bf16x8_t*>(&Bs[cur][SWZ_ELEM(row, kh * 4 + fq)]);
    }
    #pragma unroll
    for (int kh = 0; kh < 2; ++kh)
      #pragma unroll
      for (int ii = 0; ii < 2; ++ii)
        #pragma unroll
        for (int jj = 0; jj < 2; ++jj)
          acc[ii][jj] = __builtin_amdgcn_mfma_f32_16x16x32_bf16(af[ii][kh], bfr[jj][kh], acc[ii][jj], 0, 0, 0);

    if (kt < 7) WRITE_B(nxt);        // cvt + LDS write after MFMA issue
    __syncthreads();
  }
#undef STAGE_A
#undef LOAD_B
#undef WRITE_B

  // epilogue: C/D layout col=lane&15, row=(lane>>4)*4+reg
  const int q4 = fq * 4;
  #pragma unroll
  for (int jj = 0; jj < 2; ++jj) {
    const int e  = e0t + wc * 32 + jj * 16 + fr;
    const float bv = bias[p * E_ + e];
    #pragma unroll
    for (int ii = 0; ii < 2; ++ii) {
      const int r0 = b0 + wr * 32 + ii * 16 + q4;
      #pragma unroll
      for (int rg = 0; rg < 4; ++rg) {
        out[((size_t)(r0 + rg) * E_ + e) * P_ + p] = acc[ii][jj][rg] + bv;
      }
    }
  }
}

// ---------------------------------------------------------------------------
// Fallback (only if workspace is too small): naive but correct.
// ---------------------------------------------------------------------------
__global__ __launch_bounds__(256) void naive_kernel(
    const float* __restrict__ x, const float* __restrict__ W,
    const float* __restrict__ bias, float* __restrict__ out) {
  const size_t idx = (size_t)blockIdx.x * 256 + threadIdx.x;
  const int p = (int)(idx & 127);
  const int e = (int)((idx >> 7) & 127);
  const int b = (int)(idx >> 14);
  float acc = bias[p * E_ + e];
  const float* xp = x + (size_t)b * D_ * P_ + p;
  const float* wp = W + (size_t)p * D_ * E_ + e;
  for (int d = 0; d < D_; ++d) acc += xp[(size_t)d * P_] * wp[(size_t)d * E_];
  out[idx] = acc;
}

extern "C" void kernel_launch(void* const* d_in, const int* in_sizes, int n_in,
                              void* d_out, int out_size, void* d_ws, size_t ws_size,
                              hipStream_t stream) {
  (void)in_sizes; (void)n_in; (void)out_size;
  const float* x    = (const float*)d_in[0];   // [B,D,P] f32
  const float* W    = (const float*)d_in[1];   // [P,D,E] f32
  const float* bias = (const float*)d_in[2];   // [P,E]   f32
  float* out = (float*)d_out;                  // [B,E,P] f32

  const size_t xT_bytes = (size_t)P_ * B_ * D_ * 2;   // 32 MiB

  if (ws_size < xT_bytes) {
    naive_kernel<<<dim3((B_ * E_ * P_) / 256), dim3(256), 0, stream>>>(x, W, bias, out);
    return;
  }

  u16* xT = (u16*)d_ws;                                 // [P][B][D] bf16

  transpose_cvt_kernel<<<dim3(B_, 8, 2), 256, 0, stream>>>(x, xT);
  gemm_kernel<<<dim3(1024), 256, 0, stream>>>(xT, W, bias, out);
}